// Round 18
// baseline (44.845 us; speedup 1.0000x reference)
//
#include <hip/hip_runtime.h>
#include <cstdint>

#define B_ 2
#define N_ 8192
#define M_ 1024
#define C_ 1152
#define EPS_ 1e-8f
#define NT 32
#define CHUNK 128
#define NBN (N_ / NT)      // 256 n-blocks
#define NBC (C_ / CHUNK)   // 9 c-blocks
#define PTS 32             // points per threenn block
#define NSL 4              // center-table slices
#define MSL (M_ / NSL)     // 256 centers per slice
#define NNB ((N_ / PTS) * NSL * B_)        // 2048 threenn blocks
#define TRB ((M_ / 64) * (C_ / 64) * B_)   // 576 transpose blocks

typedef float f32x4 __attribute__((ext_vector_type(4)));

// bf16 helpers (RNE)
__device__ __forceinline__ unsigned short f2bf(float f) {
    unsigned u = __float_as_uint(f);
    u += 0x7fffu + ((u >> 16) & 1u);
    return (unsigned short)(u >> 16);
}
__device__ __forceinline__ float bf2f(unsigned short h) {
    return __uint_as_float(((unsigned)h) << 16);
}

// cross-candidate merge insert: lexicographic (d, then index)
__device__ __forceinline__ void ins3lex(float d, int i,
        float& d0, int& i0, float& d1, int& i1, float& d2, int& i2) {
    bool b0 = (d < d0) || (d == d0 && i < i0);
    bool b1 = (d < d1) || (d == d1 && i < i1);
    bool b2 = (d < d2) || (d == d2 && i < i2);
    d2 = b1 ? d1 : (b2 ? d : d2);   i2 = b1 ? i1 : (b2 ? i : i2);
    d1 = b0 ? d0 : (b1 ? d : d1);   i1 = b0 ? i0 : (b1 ? i : i1);
    d0 = b0 ? d  : d0;              i0 = b0 ? i  : i0;
}

// ---------------- K_front: three_nn slices (bid < NNB, fills machine first) + transpose tail ----------------
__global__ __launch_bounds__(256) void k_front(const float* __restrict__ feats,
                                               unsigned short* __restrict__ fm,
                                               const float* __restrict__ xyz,
                                               const float* __restrict__ center,
                                               float* __restrict__ cand) {
    __shared__ float4 shb[1040];   // 16.64 KB union: transpose tile[64][65] / sc[256]
    int bid = blockIdx.x;
    int t   = threadIdx.x;

    if (bid >= NNB) {
        // ---- transpose role: feats [B][C][M] f32 -> fm [B][M][C] bf16 ----
        float* tile = (float*)shb;           // [64][65]
        int tb = bid - NNB;
        int within = tb % ((M_ / 64) * (C_ / 64));
        int b  = tb / ((M_ / 64) * (C_ / 64));
        int mb = within & 15;
        int cb = within >> 4;                // 0..17
        int m0 = mb * 64;
        int c0 = cb * 64;
        int tx = t & 63;
        int ty = t >> 6;                     // 0..3
        const float* src = feats + ((size_t)b * C_ + c0) * M_ + m0;
#pragma unroll
        for (int j = 0; j < 16; ++j) {
            int cl = ty + 4 * j;
            tile[cl * 65 + tx] = __builtin_nontemporal_load(&src[(size_t)cl * M_ + tx]);
        }
        __syncthreads();
        unsigned short* dst = fm + ((size_t)b * M_ + m0) * C_ + c0;
#pragma unroll
        for (int j = 0; j < 16; ++j) {
            int ml = ty + 4 * j;
            dst[(size_t)ml * C_ + tx] = f2bf(tile[tx * 65 + ml]);
        }
        return;
    }

    // ---- three_nn slice role: 32 points x 256-center slice; 2 points share each ds_read ----
    float4* sc = shb;                        // [256] {x,y,z,|c|^2}
    int b      = bid >> 10;                  // 1024 blocks per batch
    int within = bid & 1023;
    int pg     = within >> 2;                // 0..255 point-group
    int s      = within & 3;                 // slice 0..3
    int n0     = pg * PTS;
    int msl    = s * MSL;

    // stage 1 center/thread from raw center[], cc computed exactly as ref
    {
        const float* cp = center + ((size_t)b * M_ + msl + t) * 3;
        float ax = cp[0], ay = cp[1], az = cp[2];
        float acc = __fadd_rn(__fadd_rn(__fmul_rn(ax, ax), __fmul_rn(ay, ay)),
                              __fmul_rn(az, az));
        sc[t] = make_float4(ax, ay, az, acc);
    }
    __syncthreads();

    int pp = t >> 4;    // 0..15: point-pair (points pp and pp+16)
    int c  = t & 15;    // 0..15: chunk lane
    int nA = n0 + pp;
    int nB = n0 + pp + 16;
    const float* xpA = xyz + ((size_t)b * N_ + nA) * 3;
    const float* xpB = xyz + ((size_t)b * N_ + nB) * 3;
    float xA = xpA[0], yA = xpA[1], zA = xpA[2];
    float xB = xpB[0], yB = xpB[1], zB = xpB[2];
    float xxA = __fadd_rn(__fadd_rn(__fmul_rn(xA, xA), __fmul_rn(yA, yA)),
                          __fmul_rn(zA, zA));
    float xxB = __fadd_rn(__fadd_rn(__fmul_rn(xB, xB), __fmul_rn(yB, yB)),
                          __fmul_rn(zB, zB));

    float dA0 = __builtin_inff(), dA1 = __builtin_inff(), dA2 = __builtin_inff();
    int   iA0 = 0x7fffffff,  iA1 = 0x7fffffff,  iA2 = 0x7fffffff;
    float dB0 = __builtin_inff(), dB1 = __builtin_inff(), dB2 = __builtin_inff();
    int   iB0 = 0x7fffffff,  iB1 = 0x7fffffff,  iB2 = 0x7fffffff;
#pragma unroll
    for (int it = 0; it < MSL / 16; ++it) {
        float4 v = sc[c + it * 16];          // ONE ds_read_b128 feeds TWO evals
        int   m  = msl + c + it * 16;        // increasing per lane -> strict < stable
        // ref einsum: fma dot;  d = (xx+cc) - 2*dot == fma(-2,dot,xx+cc) bit-exact
        {
            float dot = __fmaf_rn(zA, v.z, __fmaf_rn(yA, v.y, __fmul_rn(xA, v.x)));
            float d   = __fmaf_rn(-2.0f, dot, __fadd_rn(xxA, v.w));
            bool b0 = d < dA0;
            bool b1 = d < dA1;
            bool b2 = d < dA2;
            float nd0 = fminf(d, dA0);
            float nd1 = __builtin_amdgcn_fmed3f(d, dA0, dA1);
            float nd2 = __builtin_amdgcn_fmed3f(d, dA1, dA2);
            iA2 = b1 ? iA1 : (b2 ? m : iA2);
            iA1 = b0 ? iA0 : (b1 ? m : iA1);
            iA0 = b0 ? m   : iA0;
            dA0 = nd0; dA1 = nd1; dA2 = nd2;
        }
        {
            float dot = __fmaf_rn(zB, v.z, __fmaf_rn(yB, v.y, __fmul_rn(xB, v.x)));
            float d   = __fmaf_rn(-2.0f, dot, __fadd_rn(xxB, v.w));
            bool b0 = d < dB0;
            bool b1 = d < dB1;
            bool b2 = d < dB2;
            float nd0 = fminf(d, dB0);
            float nd1 = __builtin_amdgcn_fmed3f(d, dB0, dB1);
            float nd2 = __builtin_amdgcn_fmed3f(d, dB1, dB2);
            iB2 = b1 ? iB1 : (b2 ? m : iB2);
            iB1 = b0 ? iB0 : (b1 ? m : iB1);
            iB0 = b0 ? m   : iB0;
            dB0 = nd0; dB1 = nd1; dB2 = nd2;
        }
    }

    // 4-round butterfly merge within the 16-lane group (lexicographic), both triples
#pragma unroll
    for (int off = 1; off <= 8; off <<= 1) {
        float e0 = __shfl_xor(dA0, off); int j0 = __shfl_xor(iA0, off);
        float e1 = __shfl_xor(dA1, off); int j1 = __shfl_xor(iA1, off);
        float e2 = __shfl_xor(dA2, off); int j2 = __shfl_xor(iA2, off);
        ins3lex(e0, j0, dA0, iA0, dA1, iA1, dA2, iA2);
        ins3lex(e1, j1, dA0, iA0, dA1, iA1, dA2, iA2);
        ins3lex(e2, j2, dA0, iA0, dA1, iA1, dA2, iA2);
        float f0 = __shfl_xor(dB0, off); int k0 = __shfl_xor(iB0, off);
        float f1 = __shfl_xor(dB1, off); int k1 = __shfl_xor(iB1, off);
        float f2 = __shfl_xor(dB2, off); int k2 = __shfl_xor(iB2, off);
        ins3lex(f0, k0, dB0, iB0, dB1, iB1, dB2, iB2);
        ins3lex(f1, k1, dB0, iB0, dB1, iB1, dB2, iB2);
        ins3lex(f2, k2, dB0, iB0, dB1, iB1, dB2, iB2);
    }
    if (c == 0) {
        size_t baseA = (((size_t)b * N_ + nA) * NSL + s) * 6;
        cand[baseA + 0] = dA0; ((int*)cand)[baseA + 1] = iA0;
        cand[baseA + 2] = dA1; ((int*)cand)[baseA + 3] = iA1;
        cand[baseA + 4] = dA2; ((int*)cand)[baseA + 5] = iA2;
        size_t baseB = (((size_t)b * N_ + nB) * NSL + s) * 6;
        cand[baseB + 0] = dB0; ((int*)cand)[baseB + 1] = iB0;
        cand[baseB + 2] = dB1; ((int*)cand)[baseB + 3] = iB1;
        cand[baseB + 4] = dB2; ((int*)cand)[baseB + 5] = iB2;
    }
}

// ---------------- K_interp: merge slice candidates + gather(bf16) + weighted sum ----------------
__global__ __launch_bounds__(256) void k_interp(const unsigned short* __restrict__ fm,
                                                const float* __restrict__ cand,
                                                float* __restrict__ out) {
    __shared__ float T[NT][CHUNK + 1];   // stride 129
    __shared__ int   sbase[NT][3];
    __shared__ float sw[NT][3];
    int flat = blockIdx.x;
    int slot = flat & 7;
    int b    = slot >> 2;
    int idx  = (flat >> 3) * 4 + (slot & 3);   // 0..2303 per batch
    int n0   = (idx & (NBN - 1)) * NT;
    int c0   = (idx >> 8) * CHUNK;
    int t    = threadIdx.x;
    if (t < NT) {
        size_t cb = ((size_t)b * N_ + n0 + t) * (NSL * 6);
        // slice 0 triple is already sorted; fold in slices 1..3 lexicographically
        float D0 = cand[cb + 0]; int I0 = ((const int*)cand)[cb + 1];
        float D1 = cand[cb + 2]; int I1 = ((const int*)cand)[cb + 3];
        float D2 = cand[cb + 4]; int I2 = ((const int*)cand)[cb + 5];
#pragma unroll
        for (int sl = 1; sl < NSL; ++sl) {
            size_t sb = cb + sl * 6;
            ins3lex(cand[sb + 0], ((const int*)cand)[sb + 1], D0, I0, D1, I1, D2, I2);
            ins3lex(cand[sb + 2], ((const int*)cand)[sb + 3], D0, I0, D1, I1, D2, I2);
            ins3lex(cand[sb + 4], ((const int*)cand)[sb + 5], D0, I0, D1, I1, D2, I2);
        }
        float r0 = 1.0f / __fadd_rn(D0, EPS_);
        float r1 = 1.0f / __fadd_rn(D1, EPS_);
        float r2 = 1.0f / __fadd_rn(D2, EPS_);
        float s  = __fadd_rn(__fadd_rn(r0, r1), r2);
        sbase[t][0] = (b * M_ + I0) * C_;  sw[t][0] = r0 / s;
        sbase[t][1] = (b * M_ + I1) * C_;  sw[t][1] = r1 / s;
        sbase[t][2] = (b * M_ + I2) * C_;  sw[t][2] = r2 / s;
    }
    __syncthreads();
    int wave = t >> 6;
    int lane = t & 63;
    int half = lane >> 5;
    int cl   = (lane & 31) * 4;
#pragma unroll
    for (int pp = 0; pp < 4; ++pp) {
        int p = pp * 8 + wave * 2 + half;
        float w0 = sw[p][0], w1 = sw[p][1], w2 = sw[p][2];
        const ushort4 a0 = *(const ushort4*)(fm + sbase[p][0] + c0 + cl);
        const ushort4 a1 = *(const ushort4*)(fm + sbase[p][1] + c0 + cl);
        const ushort4 a2 = *(const ushort4*)(fm + sbase[p][2] + c0 + cl);
        T[p][cl + 0] = __fmaf_rn(bf2f(a2.x), w2, __fmaf_rn(bf2f(a1.x), w1, __fmul_rn(bf2f(a0.x), w0)));
        T[p][cl + 1] = __fmaf_rn(bf2f(a2.y), w2, __fmaf_rn(bf2f(a1.y), w1, __fmul_rn(bf2f(a0.y), w0)));
        T[p][cl + 2] = __fmaf_rn(bf2f(a2.z), w2, __fmaf_rn(bf2f(a1.z), w1, __fmul_rn(bf2f(a0.z), w0)));
        T[p][cl + 3] = __fmaf_rn(bf2f(a2.w), w2, __fmaf_rn(bf2f(a1.w), w1, __fmul_rn(bf2f(a0.w), w0)));
    }
    __syncthreads();
    int p4  = (t & 7) * 4;
    int ccb = t >> 3;
#pragma unroll
    for (int r = 0; r < 4; ++r) {
        int cc = r * 32 + ccb;
        f32x4 v = { T[p4 + 0][cc], T[p4 + 1][cc], T[p4 + 2][cc], T[p4 + 3][cc] };
        __builtin_nontemporal_store(v,
            (f32x4*)&out[((size_t)b * C_ + c0 + cc) * N_ + n0 + p4]);
    }
}

// ---------------- launch ----------------
extern "C" void kernel_launch(void* const* d_in, const int* in_sizes, int n_in,
                              void* d_out, int out_size, void* d_ws, size_t ws_size,
                              hipStream_t stream) {
    const float* xyz    = (const float*)d_in[0];   // [B,N,3]
    const float* center = (const float*)d_in[1];   // [B,M,3]
    const float* feats  = (const float*)d_in[2];   // [B,C,M]
    float* out = (float*)d_out;                    // [B,C,N]

    // ws: fm bf16 [B*M*C] | cand [B*N*4*6 dwords]  (~6.3 MB)
    char*           ws   = (char*)d_ws;
    unsigned short* fm   = (unsigned short*)ws;
    float*          cand = (float*)(ws + (size_t)B_ * M_ * C_ * 2);

    k_front <<<NNB + TRB, 256, 0, stream>>>(feats, fm, xyz, center, cand);
    k_interp<<<NBN * NBC * B_, 256, 0, stream>>>(fm, cand, out);
}

// Round 19
// 35.999 us; speedup vs baseline: 1.2457x; 1.2457x over previous
//
#include <hip/hip_runtime.h>
#include <cstdint>

#define B_ 2
#define N_ 8192
#define M_ 1024
#define C_ 1152
#define EPS_ 1e-8f
#define NT 32
#define CHUNK 128
#define NBN (N_ / NT)      // 256 n-blocks
#define NBC (C_ / CHUNK)   // 9 c-blocks
#define PTS 16             // points per threenn block
#define NSL 2              // center-table slices
#define MSL (M_ / NSL)     // 512 centers per slice
#define NNB ((N_ / PTS) * NSL * B_)        // 2048 threenn blocks
#define TRB ((M_ / 64) * (C_ / 64) * B_)   // 576 transpose blocks

typedef float f32x4 __attribute__((ext_vector_type(4)));

// bf16 helpers (RNE)
__device__ __forceinline__ unsigned short f2bf(float f) {
    unsigned u = __float_as_uint(f);
    u += 0x7fffu + ((u >> 16) & 1u);
    return (unsigned short)(u >> 16);
}
__device__ __forceinline__ float bf2f(unsigned short h) {
    return __uint_as_float(((unsigned)h) << 16);
}

// cross-candidate merge insert: lexicographic (d, then index)
__device__ __forceinline__ void ins3lex(float d, int i,
        float& d0, int& i0, float& d1, int& i1, float& d2, int& i2) {
    bool b0 = (d < d0) || (d == d0 && i < i0);
    bool b1 = (d < d1) || (d == d1 && i < i1);
    bool b2 = (d < d2) || (d == d2 && i < i2);
    d2 = b1 ? d1 : (b2 ? d : d2);   i2 = b1 ? i1 : (b2 ? i : i2);
    d1 = b0 ? d0 : (b1 ? d : d1);   i1 = b0 ? i0 : (b1 ? i : i1);
    d0 = b0 ? d  : d0;              i0 = b0 ? i  : i0;
}

// ---------------- K_front: three_nn slice blocks (bid < NNB) + transpose (rest) ----------------
__global__ __launch_bounds__(256) void k_front(const float* __restrict__ feats,
                                               unsigned short* __restrict__ fm,
                                               const float* __restrict__ xyz,
                                               const float* __restrict__ center,
                                               float* __restrict__ cand) {
    __shared__ float4 shb[1040];   // 16.64 KB union: transpose tile[64][65] / sc[512]
    int bid = blockIdx.x;
    int t   = threadIdx.x;

    if (bid >= NNB) {
        // ---- transpose role: feats [B][C][M] f32 -> fm [B][M][C] bf16 ----
        float* tile = (float*)shb;           // [64][65]
        int tb = bid - NNB;
        int within = tb % ((M_ / 64) * (C_ / 64));
        int b  = tb / ((M_ / 64) * (C_ / 64));
        int mb = within & 15;
        int cb = within >> 4;                // 0..17
        int m0 = mb * 64;
        int c0 = cb * 64;
        int tx = t & 63;
        int ty = t >> 6;                     // 0..3
        const float* src = feats + ((size_t)b * C_ + c0) * M_ + m0;
#pragma unroll
        for (int j = 0; j < 16; ++j) {
            int cl = ty + 4 * j;
            tile[cl * 65 + tx] = __builtin_nontemporal_load(&src[(size_t)cl * M_ + tx]);
        }
        __syncthreads();
        unsigned short* dst = fm + ((size_t)b * M_ + m0) * C_ + c0;
#pragma unroll
        for (int j = 0; j < 16; ++j) {
            int ml = ty + 4 * j;
            dst[(size_t)ml * C_ + tx] = f2bf(tile[tx * 65 + ml]);
        }
        return;
    }

    // ---- three_nn slice role: 16 points x 512-center slice; 8 blocks/CU ----
    float4* sc = shb;                        // [512] {x,y,z,|c|^2}
    int b      = bid >> 10;                  // 1024 blocks per batch
    int within = bid & 1023;
    int pg     = within >> 1;                // 0..511 point-group
    int s      = within & 1;                 // slice
    int n0     = pg * PTS;
    int msl    = s * MSL;

    // stage 2 centers/thread from raw center[], cc computed exactly as ref
    {
        int i0s = 2 * t;
        const float* cp = center + ((size_t)b * M_ + msl + i0s) * 3;
        float ax = cp[0], ay = cp[1], az = cp[2];
        float bx = cp[3], by = cp[4], bz = cp[5];
        float acc = __fadd_rn(__fadd_rn(__fmul_rn(ax, ax), __fmul_rn(ay, ay)),
                              __fmul_rn(az, az));
        float bcc = __fadd_rn(__fadd_rn(__fmul_rn(bx, bx), __fmul_rn(by, by)),
                              __fmul_rn(bz, bz));
        sc[i0s]     = make_float4(ax, ay, az, acc);
        sc[i0s + 1] = make_float4(bx, by, bz, bcc);
    }
    __syncthreads();

    int p = t >> 4;     // 0..15: point within block
    int c = t & 15;     // 0..15: chunk
    int n = n0 + p;
    float x = xyz[((size_t)b * N_ + n) * 3 + 0];
    float y = xyz[((size_t)b * N_ + n) * 3 + 1];
    float z = xyz[((size_t)b * N_ + n) * 3 + 2];
    float xx = __fadd_rn(__fadd_rn(__fmul_rn(x, x), __fmul_rn(y, y)),
                         __fmul_rn(z, z));

    float d0 = __builtin_inff(), d1 = __builtin_inff(), d2 = __builtin_inff();
    int   i0 = 0x7fffffff,  i1 = 0x7fffffff,  i2 = 0x7fffffff;
#pragma unroll 8
    for (int it = 0; it < MSL / 16; ++it) {
        float4 v = sc[c + it * 16];
        // ref einsum: fma dot;  d = (xx+cc) - 2*dot == fma(-2,dot,xx+cc) bit-exact
        float dot = __fmaf_rn(z, v.z, __fmaf_rn(y, v.y, __fmul_rn(x, v.x)));
        float s0  = __fadd_rn(xx, v.w);
        float d   = __fmaf_rn(-2.0f, dot, s0);
        int   m   = msl + c + it * 16;       // increasing per lane -> strict < stable
        bool b0 = d < d0;
        bool b1 = d < d1;
        bool b2 = d < d2;
        float nd0 = fminf(d, d0);
        float nd1 = __builtin_amdgcn_fmed3f(d, d0, d1);   // value-identical to select cascade
        float nd2 = __builtin_amdgcn_fmed3f(d, d1, d2);
        i2 = b1 ? i1 : (b2 ? m : i2);
        i1 = b0 ? i0 : (b1 ? m : i1);
        i0 = b0 ? m  : i0;
        d0 = nd0; d1 = nd1; d2 = nd2;
    }

    // 4-round butterfly merge within the 16-lane group (lexicographic)
#pragma unroll
    for (int off = 1; off <= 8; off <<= 1) {
        float e0 = __shfl_xor(d0, off); int j0 = __shfl_xor(i0, off);
        float e1 = __shfl_xor(d1, off); int j1 = __shfl_xor(i1, off);
        float e2 = __shfl_xor(d2, off); int j2 = __shfl_xor(i2, off);
        ins3lex(e0, j0, d0, i0, d1, i1, d2, i2);
        ins3lex(e1, j1, d0, i0, d1, i1, d2, i2);
        ins3lex(e2, j2, d0, i0, d1, i1, d2, i2);
    }
    if (c == 0) {
        size_t base = (((size_t)b * N_ + n) * NSL + s) * 6;
        cand[base + 0] = d0; ((int*)cand)[base + 1] = i0;
        cand[base + 2] = d1; ((int*)cand)[base + 3] = i1;
        cand[base + 4] = d2; ((int*)cand)[base + 5] = i2;
    }
}

// ---------------- K_interp: merge slice candidates + gather(bf16) + weighted sum ----------------
__global__ __launch_bounds__(256) void k_interp(const unsigned short* __restrict__ fm,
                                                const float* __restrict__ cand,
                                                float* __restrict__ out) {
    __shared__ float T[NT][CHUNK + 1];   // stride 129
    __shared__ int   sbase[NT][3];
    __shared__ float sw[NT][3];
    int flat = blockIdx.x;
    int slot = flat & 7;
    int b    = slot >> 2;
    int idx  = (flat >> 3) * 4 + (slot & 3);   // 0..2303 per batch
    int n0   = (idx & (NBN - 1)) * NT;
    int c0   = (idx >> 8) * CHUNK;
    int t    = threadIdx.x;
    if (t < NT) {
        size_t cb = ((size_t)b * N_ + n0 + t) * (NSL * 6);
        // slice 0 triple is already sorted; fold in slice 1 lexicographically
        float D0 = cand[cb + 0]; int I0 = ((const int*)cand)[cb + 1];
        float D1 = cand[cb + 2]; int I1 = ((const int*)cand)[cb + 3];
        float D2 = cand[cb + 4]; int I2 = ((const int*)cand)[cb + 5];
        ins3lex(cand[cb + 6],  ((const int*)cand)[cb + 7],  D0, I0, D1, I1, D2, I2);
        ins3lex(cand[cb + 8],  ((const int*)cand)[cb + 9],  D0, I0, D1, I1, D2, I2);
        ins3lex(cand[cb + 10], ((const int*)cand)[cb + 11], D0, I0, D1, I1, D2, I2);
        float r0 = 1.0f / __fadd_rn(D0, EPS_);
        float r1 = 1.0f / __fadd_rn(D1, EPS_);
        float r2 = 1.0f / __fadd_rn(D2, EPS_);
        float s  = __fadd_rn(__fadd_rn(r0, r1), r2);
        sbase[t][0] = (b * M_ + I0) * C_;  sw[t][0] = r0 / s;
        sbase[t][1] = (b * M_ + I1) * C_;  sw[t][1] = r1 / s;
        sbase[t][2] = (b * M_ + I2) * C_;  sw[t][2] = r2 / s;
    }
    __syncthreads();
    int wave = t >> 6;
    int lane = t & 63;
    int half = lane >> 5;
    int cl   = (lane & 31) * 4;
#pragma unroll
    for (int pp = 0; pp < 4; ++pp) {
        int p = pp * 8 + wave * 2 + half;
        float w0 = sw[p][0], w1 = sw[p][1], w2 = sw[p][2];
        const ushort4 a0 = *(const ushort4*)(fm + sbase[p][0] + c0 + cl);
        const ushort4 a1 = *(const ushort4*)(fm + sbase[p][1] + c0 + cl);
        const ushort4 a2 = *(const ushort4*)(fm + sbase[p][2] + c0 + cl);
        T[p][cl + 0] = __fmaf_rn(bf2f(a2.x), w2, __fmaf_rn(bf2f(a1.x), w1, __fmul_rn(bf2f(a0.x), w0)));
        T[p][cl + 1] = __fmaf_rn(bf2f(a2.y), w2, __fmaf_rn(bf2f(a1.y), w1, __fmul_rn(bf2f(a0.y), w0)));
        T[p][cl + 2] = __fmaf_rn(bf2f(a2.z), w2, __fmaf_rn(bf2f(a1.z), w1, __fmul_rn(bf2f(a0.z), w0)));
        T[p][cl + 3] = __fmaf_rn(bf2f(a2.w), w2, __fmaf_rn(bf2f(a1.w), w1, __fmul_rn(bf2f(a0.w), w0)));
    }
    __syncthreads();
    int p4  = (t & 7) * 4;
    int ccb = t >> 3;
#pragma unroll
    for (int r = 0; r < 4; ++r) {
        int cc = r * 32 + ccb;
        f32x4 v = { T[p4 + 0][cc], T[p4 + 1][cc], T[p4 + 2][cc], T[p4 + 3][cc] };
        __builtin_nontemporal_store(v,
            (f32x4*)&out[((size_t)b * C_ + c0 + cc) * N_ + n0 + p4]);
    }
}

// ---------------- launch ----------------
extern "C" void kernel_launch(void* const* d_in, const int* in_sizes, int n_in,
                              void* d_out, int out_size, void* d_ws, size_t ws_size,
                              hipStream_t stream) {
    const float* xyz    = (const float*)d_in[0];   // [B,N,3]
    const float* center = (const float*)d_in[1];   // [B,M,3]
    const float* feats  = (const float*)d_in[2];   // [B,C,M]
    float* out = (float*)d_out;                    // [B,C,N]

    // ws: fm bf16 [B*M*C] | cand [B*N*2*6 dwords]  (~5.5 MB)
    char*           ws   = (char*)d_ws;
    unsigned short* fm   = (unsigned short*)ws;
    float*          cand = (float*)(ws + (size_t)B_ * M_ * C_ * 2);

    k_front <<<NNB + TRB, 256, 0, stream>>>(feats, fm, xyz, center, cand);
    k_interp<<<NBN * NBC * B_, 256, 0, stream>>>(fm, cand, out);
}